// Round 8
// baseline (184.889 us; speedup 1.0000x reference)
//
#include <hip/hip_runtime.h>
#include <hip/hip_bf16.h>

#define B_ 8192
#define I_ 512
#define H_ 1024
#define R_ 64

typedef __bf16 bf16x8 __attribute__((ext_vector_type(8)));
typedef short  s16x8  __attribute__((ext_vector_type(8)));
typedef float  f32x4  __attribute__((ext_vector_type(4)));

static __device__ __forceinline__ short f2bf(float f) {
    union { float f; unsigned u; } v; v.f = f;
    unsigned r = v.u + 0x7fffu + ((v.u >> 16) & 1u);
    return (short)(r >> 16);
}
// v_rcp_f32 (~1 ulp) instead of IEEE divide (no -ffast-math in harness).
static __device__ __forceinline__ float frcp_(float x) {
#if __has_builtin(__builtin_amdgcn_rcpf)
    return __builtin_amdgcn_rcpf(x);
#else
    float r; asm("v_rcp_f32 %0, %1" : "=v"(r) : "v"(x)); return r;
#endif
}
static __device__ __forceinline__ float sigmoidf_(float v) {
    return frcp_(1.f + __expf(-v));
}
static __device__ __forceinline__ float tanhf_(float v) {
    return 2.f / (1.f + __expf(-2.f * v)) - 1.f;
}
static __device__ __forceinline__ float tanhr_(float v) {
    return 2.f * frcp_(1.f + __expf(-2.f * v)) - 1.f;
}

// ---------------------------------------------------------------------------
// Prep: uxT[64][512], uhT[64][1024], Vc[4096][128] (all bf16), coef_x[4][512],
// coef_h[4][1024] (f32). Coef section: one wave per j, lanes = rank r.
// (Byte-identical to R2/R6/R7.)
// ---------------------------------------------------------------------------
__global__ __launch_bounds__(256) void prep_kernel(
    const float* __restrict__ u_x, const float* __restrict__ u_h,
    const float* __restrict__ v_x, const float* __restrict__ v_h,
    short* __restrict__ uxT, short* __restrict__ uhT, short* __restrict__ Vc,
    float* __restrict__ coef_x, float* __restrict__ coef_h)
{
    int t = blockIdx.x * 256 + threadIdx.x;
    if (t < 64 * 512) {                       // uxT[r][k] = u_x[k][r], coalesced read
        int k = t >> 6, r = t & 63;
        uxT[r * 512 + k] = f2bf(u_x[t]);
        return;
    }
    t -= 64 * 512;
    if (t < 64 * 1024) {                      // uhT[r][k] = u_h[k][r]
        int k = t >> 6, r = t & 63;
        uhT[r * 1024 + k] = f2bf(u_h[t]);
        return;
    }
    t -= 64 * 1024;
    if (t < 4096 * 128) {                     // Vc = [v_x | v_h] rows, bf16
        int n = t >> 7, q = t & 127;
        Vc[t] = f2bf(q < 64 ? v_x[n * 64 + q] : v_h[n * 64 + (q - 64)]);
        return;
    }
    t -= 4096 * 128;
    if (t < 1536 * 64) {                      // coef: 1536 waves, one j each
        const int wid = t >> 6, lane = t & 63;
        const float* U; const float* V; float* C; int j, JN;
        if (wid < 512) { U = u_x; V = v_x; C = coef_x; j = wid;       JN = 512;  }
        else           { U = u_h; V = v_h; C = coef_h; j = wid - 512; JN = 1024; }
        const float uv = U[(size_t)j * 64 + lane];
        float s[4];
#pragma unroll
        for (int g = 0; g < 4; ++g)
            s[g] = uv * V[(size_t)(g * H_ + j) * 64 + lane];
#pragma unroll
        for (int off = 32; off >= 1; off >>= 1)
#pragma unroll
            for (int g = 0; g < 4; ++g)
                s[g] += __shfl_xor(s[g], off, 64);
        if (lane == 0)
#pragma unroll
            for (int g = 0; g < 4; ++g)
                C[g * JN + j] = s[g];
        return;
    }
}

// ---------------------------------------------------------------------------
// Stage 1: P[b][0:64] = x @ u_x, P[b][64:128] = h @ u_h  (bf16 MFMA).
// CHANGE vs R7: double-buffered At[2] with ONE barrier per K-chunk (was 2).
// Sequence per chunk: convert+ds_write At[ch&1] -> prefetch next chunk's
// global loads -> __syncthreads -> MFMA reads At[ch&1]. Writes to At[b]
// at chunk ch+2 are separated from chunk-ch readers by the ch+1 barrier
// (each thread's reads drain at its own s_waitcnt before the barrier).
// Global loads now lead their consumption by a FULL chunk.
// 256-thr blocks (4 waves), 16 batch rows per block -> grid (512, 2).
// ---------------------------------------------------------------------------
__global__ __launch_bounds__(256) void stage1_kernel(
    const float* __restrict__ x, const float* __restrict__ h,
    const short* __restrict__ uxT, const short* __restrict__ uhT,
    short* __restrict__ P)
{
    __shared__ short At[2][16 * 136];
    const int w = threadIdx.x >> 6, lane = threadIdx.x & 63;
    const int quad = lane >> 4, lr = lane & 15;
    const int n0 = w * 16;

    const float* X; const short* UT; int K, co;
    if (blockIdx.y == 0) { X = x; UT = uxT; K = I_; co = 0; }
    else                 { X = h; UT = uhT; K = H_; co = 64; }

    const int b0 = blockIdx.x * 16;
    const int srow = threadIdx.x >> 4;
    const int scol = (threadIdx.x & 15) * 8;

    f32x4 acc = {};
    const short* bp = UT + (size_t)(n0 + lr) * K + quad * 8;
    const float* srcbase = X + (size_t)(b0 + srow) * K + scol;

    float4 c0 = ((const float4*)(srcbase))[0];
    float4 c1 = ((const float4*)(srcbase))[1];

    const int NCH = K >> 7;
    for (int ch = 0; ch < NCH; ++ch) {
        const int buf = ch & 1;
        s16x8 p;
        p[0] = f2bf(c0.x); p[1] = f2bf(c0.y); p[2] = f2bf(c0.z); p[3] = f2bf(c0.w);
        p[4] = f2bf(c1.x); p[5] = f2bf(c1.y); p[6] = f2bf(c1.z); p[7] = f2bf(c1.w);
        *(s16x8*)(At[buf] + srow * 136 + scol) = p;
        if (ch + 1 < NCH) {
            c0 = ((const float4*)(srcbase + (ch + 1) * 128))[0];
            c1 = ((const float4*)(srcbase + (ch + 1) * 128))[1];
        }
        __syncthreads();
        const short* arow = At[buf] + lr * 136 + quad * 8;
#pragma unroll
        for (int ks = 0; ks < 4; ++ks) {
            bf16x8 bfrag = *(const bf16x8*)(bp + ch * 128 + ks * 32);
            bf16x8 afrag = *(const bf16x8*)(arow + ks * 32);
            acc = __builtin_amdgcn_mfma_f32_16x16x32_bf16(afrag, bfrag, acc, 0, 0, 0);
        }
    }

#pragma unroll
    for (int r = 0; r < 4; ++r)
        P[(size_t)(b0 + quad * 4 + r) * 128 + co + n0 + lr] = f2bf(acc[r]);
}

// ---------------------------------------------------------------------------
// Stage 2: gates = P @ Vc^T + fused LSTM epilogue, LDS-staged epilogue I/O.
// = R7 (best: 50 us) with DEPTH-2 register staging: tile t+2's x/h/c loads
// are issued at iter t and ds_written at iter t+1 -> slack grows from
// ~epilogue-only (R7: marginal vs L3 latency, vmcnt stall at every ds_write)
// to ~1.5 iterations; the intervening barrier has already drained the loads
// so the ds_write issues stall-free. Loop fully unrolled so all reg-array
// indices are static (no scratch). Everything else identical to R7.
// Grid (64, 16), 256 thr = 4 waves; LDS 43.5 KB.
// ---------------------------------------------------------------------------
__global__ __launch_bounds__(256) void stage2_kernel(
    const short* __restrict__ P, const short* __restrict__ Vc,
    const float* __restrict__ x, const float* __restrict__ h,
    const float* __restrict__ c,
    const float* __restrict__ coef_x, const float* __restrict__ coef_h,
    const float* __restrict__ b_x, const float* __restrict__ b_h,
    const float* __restrict__ dia_x, const float* __restrict__ dia_h,
    float* __restrict__ out)
{
    __shared__ float inx[2][16 * 68];
    __shared__ float inh[2][16 * 68];
    __shared__ float inc[2][16 * 68];
    __shared__ float oh_[2][16 * 68];
    __shared__ float oc_[2][16 * 68];

    const int tid  = threadIdx.x;
    const int lane = tid & 63,  wv = tid >> 6;
    const int quad = lane >> 4, lr = lane & 15;
    const int b0  = blockIdx.x * 128;               // block's 128 batch rows
    const int j0b = blockIdx.y * 64;                // block's 64-wide j span
    const int j0  = j0b + wv * 16;                  // wave's j-tile
    const int j   = j0 + lr;
    const bool jx = (j0b < I_);                     // block-uniform

    const int srow = tid >> 4;                      // coop I/O: row 0..15
    const int scol = (tid & 15) * 4;                // coop I/O: j offset
    const int sidx = srow * 68 + scol;              // padded LDS float index
    const int jl   = wv * 16 + lr;                  // lane's local j column

    // ---- prologue: issue tile-0 AND tile-1 staging loads first
    f32x4 sx[2] = {}, sh[2], sc[2];
#pragma unroll
    for (int t = 0; t < 2; ++t) {
        const int gr = b0 + t * 16 + srow;
        sc[t] = *(const f32x4*)(c + (size_t)gr * H_ + j0b + scol);
        sh[t] = *(const f32x4*)(h + (size_t)gr * H_ + j0b + scol);
        if (jx) sx[t] = *(const f32x4*)(x + (size_t)gr * I_ + j0b + scol);
    }

    // ---- Vc fragments: 4 gates x 4 k-slices, VGPR-resident for block life
    bf16x8 bfr[4][4];
#pragma unroll
    for (int g = 0; g < 4; ++g)
#pragma unroll
        for (int ks = 0; ks < 4; ++ks)
            bfr[g][ks] = *(const bf16x8*)(Vc + (size_t)(g * H_ + j0 + lr) * 128 + ks * 32 + quad * 8);

    // per-j (lane-constant) small operands — L2-hot
    const float dx = jx ? dia_x[j] : 0.f;
    const float dh = dia_h[j];
    float cx[4], ch[4], bsum[4];
#pragma unroll
    for (int g = 0; g < 4; ++g) {
        cx[g]   = jx ? coef_x[g * I_ + j] : 0.f;
        ch[g]   = coef_h[g * H_ + j];
        bsum[g] = b_x[g * H_ + j] + b_h[g * H_ + j];
    }

    // P fragments for m-tile 0
    bf16x8 a[4];
#pragma unroll
    for (int ks = 0; ks < 4; ++ks)
        a[ks] = *(const bf16x8*)(P + (size_t)(b0 + lr) * 128 + ks * 32 + quad * 8);

    // tile-0 staged regs -> LDS buffer 0
    *(f32x4*)&inc[0][sidx] = sc[0];
    *(f32x4*)&inh[0][sidx] = sh[0];
    if (jx) *(f32x4*)&inx[0][sidx] = sx[0];

#pragma unroll
    for (int mt = 0; mt < 8; ++mt) {
        const int buf = mt & 1;

        // MFMA: all-register, D[b][j]
        f32x4 acc[4] = {};
#pragma unroll
        for (int ks = 0; ks < 4; ++ks)
#pragma unroll
            for (int g = 0; g < 4; ++g)
                acc[g] = __builtin_amdgcn_mfma_f32_16x16x32_bf16(a[ks], bfr[g][ks], acc[g], 0, 0, 0);

        __syncthreads();   // in[buf] ready (written iter mt-1); prev out visible

        // P prefetch for mt+1
        bf16x8 an[4];
        if (mt < 7) {
            const int rb = b0 + (mt + 1) * 16 + lr;
#pragma unroll
            for (int ks = 0; ks < 4; ++ks)
                an[ks] = *(const bf16x8*)(P + (size_t)rb * 128 + ks * 32 + quad * 8);
        }
        // issue tile (mt+2) staging loads into the slot consumed last iter
        if (mt < 6) {
            const int gr = b0 + (mt + 2) * 16 + srow;
            sc[buf] = *(const f32x4*)(c + (size_t)gr * H_ + j0b + scol);
            sh[buf] = *(const f32x4*)(h + (size_t)gr * H_ + j0b + scol);
            if (jx) sx[buf] = *(const f32x4*)(x + (size_t)gr * I_ + j0b + scol);
        }

        // cooperative store of PREVIOUS out tile: 4 rows x 256 B per wave instr
        if (mt > 0) {
            const int gr = b0 + (mt - 1) * 16 + srow;
            const int pb = buf ^ 1;
            f32x4 vh = *(const f32x4*)&oh_[pb][sidx];
            f32x4 vc = *(const f32x4*)&oc_[pb][sidx];
            *(f32x4*)(out + (size_t)gr * H_ + j0b + scol) = vh;
            *(f32x4*)(out + (size_t)B_ * H_ + (size_t)gr * H_ + j0b + scol) = vc;
        }

        // epilogue: per-lane scalars from LDS (2-way bank max via stride 68)
#pragma unroll
        for (int r = 0; r < 4; ++r) {
            const int rl = quad * 4 + r;
            const float xe = jx ? inx[buf][rl * 68 + jl] : 0.f;
            const float he = inh[buf][rl * 68 + jl];
            const float ce = inc[buf][rl * 68 + jl];
            const float z  = dx * xe + dh * he;

            const float g0 = acc[0][r] - xe * cx[0] - he * ch[0] + bsum[0] + z;
            const float g1 = acc[1][r] - xe * cx[1] - he * ch[1] + bsum[1] + z;
            const float g2 = acc[2][r] - xe * cx[2] - he * ch[2] + bsum[2] + z;
            const float g3 = acc[3][r] - xe * cx[3] - he * ch[3] + bsum[3] + z;

            const float ig = sigmoidf_(g0);
            const float fg = sigmoidf_(g1);
            const float og = sigmoidf_(g2);
            const float ng = tanhr_(g3);

            const float cn  = fg * ce + ig * ng;
            const float hnv = og * tanhr_(cn);

            oh_[buf][rl * 68 + jl] = hnv;
            oc_[buf][rl * 68 + jl] = cn;
        }

        // ds_write tile (mt+1): regs loaded at iter mt-1 -> already drained
        if (mt < 7) {
            const int nb = buf ^ 1;
            *(f32x4*)&inc[nb][sidx] = sc[nb];
            *(f32x4*)&inh[nb][sidx] = sh[nb];
            if (jx) *(f32x4*)&inx[nb][sidx] = sx[nb];
#pragma unroll
            for (int ks = 0; ks < 4; ++ks) a[ks] = an[ks];
        }
    }

    __syncthreads();
    {   // final out tile (mt = 7, buffer 1)
        const int gr = b0 + 7 * 16 + srow;
        f32x4 vh = *(const f32x4*)&oh_[1][sidx];
        f32x4 vc = *(const f32x4*)&oc_[1][sidx];
        *(f32x4*)(out + (size_t)gr * H_ + j0b + scol) = vh;
        *(f32x4*)(out + (size_t)B_ * H_ + (size_t)gr * H_ + j0b + scol) = vc;
    }
}

// ---------------------------------------------------------------------------
extern "C" void kernel_launch(void* const* d_in, const int* in_sizes, int n_in,
                              void* d_out, int out_size, void* d_ws, size_t ws_size,
                              hipStream_t stream) {
    const float* x     = (const float*)d_in[0];
    const float* h     = (const float*)d_in[1];
    const float* c     = (const float*)d_in[2];
    const float* u_x   = (const float*)d_in[3];
    const float* u_h   = (const float*)d_in[4];
    const float* v_x   = (const float*)d_in[5];
    const float* v_h   = (const float*)d_in[6];
    const float* b_x   = (const float*)d_in[7];
    const float* b_h   = (const float*)d_in[8];
    const float* dia_x = (const float*)d_in[9];
    const float* dia_h = (const float*)d_in[10];
    float* out = (float*)d_out;

    char* ws = (char*)d_ws;
    short* P      = (short*)(ws);                                    // 2,097,152 B
    short* uxT    = (short*)(ws + 2097152);                          //    65,536
    short* uhT    = (short*)(ws + 2097152 + 65536);                  //   131,072
    short* Vc     = (short*)(ws + 2097152 + 65536 + 131072);         // 1,048,576
    float* coef_x = (float*)(ws + 2097152 + 65536 + 131072 + 1048576);
    float* coef_h = (float*)(ws + 2097152 + 65536 + 131072 + 1048576 + 8192);

    prep_kernel<<<2816, 256, 0, stream>>>(u_x, u_h, v_x, v_h, uxT, uhT, Vc, coef_x, coef_h);
    stage1_kernel<<<dim3(512, 2), 256, 0, stream>>>(x, h, uxT, uhT, P);
    stage2_kernel<<<dim3(64, 16), 256, 0, stream>>>(P, Vc, x, h, c,
                                                    coef_x, coef_h, b_x, b_h,
                                                    dia_x, dia_h, out);
}

// Round 9
// 182.788 us; speedup vs baseline: 1.0115x; 1.0115x over previous
//
#include <hip/hip_runtime.h>
#include <hip/hip_bf16.h>

#define B_ 8192
#define I_ 512
#define H_ 1024
#define R_ 64

typedef __bf16 bf16x8 __attribute__((ext_vector_type(8)));
typedef short  s16x8  __attribute__((ext_vector_type(8)));
typedef float  f32x4  __attribute__((ext_vector_type(4)));

static __device__ __forceinline__ short f2bf(float f) {
    union { float f; unsigned u; } v; v.f = f;
    unsigned r = v.u + 0x7fffu + ((v.u >> 16) & 1u);
    return (short)(r >> 16);
}
// v_rcp_f32 (~1 ulp) instead of IEEE divide (no -ffast-math in harness).
static __device__ __forceinline__ float frcp_(float x) {
#if __has_builtin(__builtin_amdgcn_rcpf)
    return __builtin_amdgcn_rcpf(x);
#else
    float r; asm("v_rcp_f32 %0, %1" : "=v"(r) : "v"(x)); return r;
#endif
}
static __device__ __forceinline__ float sigmoidf_(float v) {
    return frcp_(1.f + __expf(-v));
}
static __device__ __forceinline__ float tanhr_(float v) {
    return 2.f * frcp_(1.f + __expf(-2.f * v)) - 1.f;
}

// ---------------------------------------------------------------------------
// Prep: uxT[64][512], uhT[64][1024], Vc[4096][128] (all bf16), coef_x[4][512],
// coef_h[4][1024] (f32). Coef section: one wave per j, lanes = rank r.
// (Byte-identical to R2/R6/R7/R8.)
// ---------------------------------------------------------------------------
__global__ __launch_bounds__(256) void prep_kernel(
    const float* __restrict__ u_x, const float* __restrict__ u_h,
    const float* __restrict__ v_x, const float* __restrict__ v_h,
    short* __restrict__ uxT, short* __restrict__ uhT, short* __restrict__ Vc,
    float* __restrict__ coef_x, float* __restrict__ coef_h)
{
    int t = blockIdx.x * 256 + threadIdx.x;
    if (t < 64 * 512) {                       // uxT[r][k] = u_x[k][r], coalesced read
        int k = t >> 6, r = t & 63;
        uxT[r * 512 + k] = f2bf(u_x[t]);
        return;
    }
    t -= 64 * 512;
    if (t < 64 * 1024) {                      // uhT[r][k] = u_h[k][r]
        int k = t >> 6, r = t & 63;
        uhT[r * 1024 + k] = f2bf(u_h[t]);
        return;
    }
    t -= 64 * 1024;
    if (t < 4096 * 128) {                     // Vc = [v_x | v_h] rows, bf16
        int n = t >> 7, q = t & 127;
        Vc[t] = f2bf(q < 64 ? v_x[n * 64 + q] : v_h[n * 64 + (q - 64)]);
        return;
    }
    t -= 4096 * 128;
    if (t < 1536 * 64) {                      // coef: 1536 waves, one j each
        const int wid = t >> 6, lane = t & 63;
        const float* U; const float* V; float* C; int j, JN;
        if (wid < 512) { U = u_x; V = v_x; C = coef_x; j = wid;       JN = 512;  }
        else           { U = u_h; V = v_h; C = coef_h; j = wid - 512; JN = 1024; }
        const float uv = U[(size_t)j * 64 + lane];
        float s[4];
#pragma unroll
        for (int g = 0; g < 4; ++g)
            s[g] = uv * V[(size_t)(g * H_ + j) * 64 + lane];
#pragma unroll
        for (int off = 32; off >= 1; off >>= 1)
#pragma unroll
            for (int g = 0; g < 4; ++g)
                s[g] += __shfl_xor(s[g], off, 64);
        if (lane == 0)
#pragma unroll
            for (int g = 0; g < 4; ++g)
                C[g * JN + j] = s[g];
        return;
    }
}

// ---------------------------------------------------------------------------
// Stage 1: P[b][0:64] = x @ u_x, P[b][64:128] = h @ u_h  (bf16 MFMA).
// Double-buffered At[2], one barrier per K-chunk (R8 version, kept).
// 256-thr blocks (4 waves), 16 batch rows per block -> grid (512, 2).
// ---------------------------------------------------------------------------
__global__ __launch_bounds__(256) void stage1_kernel(
    const float* __restrict__ x, const float* __restrict__ h,
    const short* __restrict__ uxT, const short* __restrict__ uhT,
    short* __restrict__ P)
{
    __shared__ short At[2][16 * 136];
    const int w = threadIdx.x >> 6, lane = threadIdx.x & 63;
    const int quad = lane >> 4, lr = lane & 15;
    const int n0 = w * 16;

    const float* X; const short* UT; int K, co;
    if (blockIdx.y == 0) { X = x; UT = uxT; K = I_; co = 0; }
    else                 { X = h; UT = uhT; K = H_; co = 64; }

    const int b0 = blockIdx.x * 16;
    const int srow = threadIdx.x >> 4;
    const int scol = (threadIdx.x & 15) * 8;

    f32x4 acc = {};
    const short* bp = UT + (size_t)(n0 + lr) * K + quad * 8;
    const float* srcbase = X + (size_t)(b0 + srow) * K + scol;

    float4 c0 = ((const float4*)(srcbase))[0];
    float4 c1 = ((const float4*)(srcbase))[1];

    const int NCH = K >> 7;
    for (int ch = 0; ch < NCH; ++ch) {
        const int buf = ch & 1;
        s16x8 p;
        p[0] = f2bf(c0.x); p[1] = f2bf(c0.y); p[2] = f2bf(c0.z); p[3] = f2bf(c0.w);
        p[4] = f2bf(c1.x); p[5] = f2bf(c1.y); p[6] = f2bf(c1.z); p[7] = f2bf(c1.w);
        *(s16x8*)(At[buf] + srow * 136 + scol) = p;
        if (ch + 1 < NCH) {
            c0 = ((const float4*)(srcbase + (ch + 1) * 128))[0];
            c1 = ((const float4*)(srcbase + (ch + 1) * 128))[1];
        }
        __syncthreads();
        const short* arow = At[buf] + lr * 136 + quad * 8;
#pragma unroll
        for (int ks = 0; ks < 4; ++ks) {
            bf16x8 bfrag = *(const bf16x8*)(bp + ch * 128 + ks * 32);
            bf16x8 afrag = *(const bf16x8*)(arow + ks * 32);
            acc = __builtin_amdgcn_mfma_f32_16x16x32_bf16(afrag, bfrag, acc, 0, 0, 0);
        }
    }

#pragma unroll
    for (int r = 0; r < 4; ++r)
        P[(size_t)(b0 + quad * 4 + r) * 128 + co + n0 + lr] = f2bf(acc[r]);
}

// ---------------------------------------------------------------------------
// Stage 2: gates = P @ Vc^T + fused LSTM epilogue.
// HYBRID of R6 + R7, motivated by counters:
//   - R6->R7 showed coop INPUT staging changed FETCH_SIZE not at all (reads
//     already L3-absorbed) but coop OUTPUT staging snapped WRITE_SIZE to
//     exactly 64 MB. So: inputs per-lane in registers (R6 path), outputs
//     through LDS coop stores (R7 path).
//   - LDS drops 43.5 KB -> 17 KB: blocks/CU by LDS 3 -> 9; grid (64,16) =
//     4 blocks/CU -> ALL 16 waves/CU resident (R7/R8 measured only ~5.3
//     waves/CU = 1.3/SIMD, every memory latency exposed; R8's deeper
//     pipelining null -> residency, not issue slack, is the limiter).
// Per m-tile: prefetch next P-frags + x/h/c scalars -> MFMA -> barrier ->
// coop-store prev out tile (4 rows x 256 B per wave instr) -> epilogue
// writes h'/c' to LDS (stride-68 pad, 2-way max). One barrier/iter,
// out tiles double-buffered. Grid (64, 16), 256 thr = 4 waves.
// ---------------------------------------------------------------------------
__global__ __launch_bounds__(256) void stage2_kernel(
    const short* __restrict__ P, const short* __restrict__ Vc,
    const float* __restrict__ x, const float* __restrict__ h,
    const float* __restrict__ c,
    const float* __restrict__ coef_x, const float* __restrict__ coef_h,
    const float* __restrict__ b_x, const float* __restrict__ b_h,
    const float* __restrict__ dia_x, const float* __restrict__ dia_h,
    float* __restrict__ out)
{
    __shared__ float oh_[2][16 * 68];
    __shared__ float oc_[2][16 * 68];

    const int tid  = threadIdx.x;
    const int lane = tid & 63,  wv = tid >> 6;
    const int quad = lane >> 4, lr = lane & 15;
    const int b0  = blockIdx.x * 128;               // block's 128 batch rows
    const int j0b = blockIdx.y * 64;                // block's 64-wide j span
    const int j0  = j0b + wv * 16;                  // wave's j-tile
    const int j   = j0 + lr;
    const bool jx = (j0b < I_);                     // block-uniform

    const int srow = tid >> 4;                      // coop store: row 0..15
    const int scol = (tid & 15) * 4;                // coop store: j offset
    const int sidx = srow * 68 + scol;              // padded LDS float index
    const int jl   = wv * 16 + lr;                  // lane's local j column

    // ---- Vc fragments: 4 gates x 4 k-slices, VGPR-resident for block life
    bf16x8 bfr[4][4];
#pragma unroll
    for (int g = 0; g < 4; ++g)
#pragma unroll
        for (int ks = 0; ks < 4; ++ks)
            bfr[g][ks] = *(const bf16x8*)(Vc + (size_t)(g * H_ + j0 + lr) * 128 + ks * 32 + quad * 8);

    // per-j (lane-constant) small operands — L2-hot
    const float dx = jx ? dia_x[j] : 0.f;
    const float dh = dia_h[j];
    float cx[4], ch[4], bsum[4];
#pragma unroll
    for (int g = 0; g < 4; ++g) {
        cx[g]   = jx ? coef_x[g * I_ + j] : 0.f;
        ch[g]   = coef_h[g * H_ + j];
        bsum[g] = b_x[g * H_ + j] + b_h[g * H_ + j];
    }

    // prologue: P fragments + per-lane x/h/c for m-tile 0
    bf16x8 a[4];
#pragma unroll
    for (int ks = 0; ks < 4; ++ks)
        a[ks] = *(const bf16x8*)(P + (size_t)(b0 + lr) * 128 + ks * 32 + quad * 8);
    float xv[4], hv[4], cv[4];
#pragma unroll
    for (int r = 0; r < 4; ++r) {
        const int brow = b0 + quad * 4 + r;
        cv[r] = c[(size_t)brow * H_ + j];
        hv[r] = h[(size_t)brow * H_ + j];
        xv[r] = jx ? x[(size_t)brow * I_ + j] : 0.f;
    }

#pragma unroll
    for (int mt = 0; mt < 8; ++mt) {
        const int buf = mt & 1;

        // prefetch next m-tile's P-fragments + epilogue operands (R6 path)
        bf16x8 an[4];
        float xn[4], hn[4], cn2[4];
        if (mt < 7) {
            const int rb = b0 + (mt + 1) * 16;
#pragma unroll
            for (int ks = 0; ks < 4; ++ks)
                an[ks] = *(const bf16x8*)(P + (size_t)(rb + lr) * 128 + ks * 32 + quad * 8);
#pragma unroll
            for (int r = 0; r < 4; ++r) {
                const int brow = rb + quad * 4 + r;
                cn2[r] = c[(size_t)brow * H_ + j];
                hn[r]  = h[(size_t)brow * H_ + j];
                xn[r]  = jx ? x[(size_t)brow * I_ + j] : 0.f;
            }
        }

        // MFMA: A and B both from registers
        f32x4 acc[4] = {};
#pragma unroll
        for (int ks = 0; ks < 4; ++ks)
#pragma unroll
            for (int g = 0; g < 4; ++g)
                acc[g] = __builtin_amdgcn_mfma_f32_16x16x32_bf16(a[ks], bfr[g][ks], acc[g], 0, 0, 0);

        __syncthreads();   // prev tile's oh_/oc_ writes visible block-wide

        // cooperative store of PREVIOUS out tile: 4 rows x 256 B per wave instr
        if (mt > 0) {
            const int gr = b0 + (mt - 1) * 16 + srow;
            const int pb = buf ^ 1;
            f32x4 vh = *(const f32x4*)&oh_[pb][sidx];
            f32x4 vc = *(const f32x4*)&oc_[pb][sidx];
            *(f32x4*)(out + (size_t)gr * H_ + j0b + scol) = vh;
            *(f32x4*)(out + (size_t)B_ * H_ + (size_t)gr * H_ + j0b + scol) = vc;
        }

        // epilogue: per-lane scalars, results into LDS (stride-68: 2-way max)
#pragma unroll
        for (int r = 0; r < 4; ++r) {
            const int rl = quad * 4 + r;
            const float xe = xv[r], he = hv[r];
            const float z  = dx * xe + dh * he;

            const float g0 = acc[0][r] - xe * cx[0] - he * ch[0] + bsum[0] + z;
            const float g1 = acc[1][r] - xe * cx[1] - he * ch[1] + bsum[1] + z;
            const float g2 = acc[2][r] - xe * cx[2] - he * ch[2] + bsum[2] + z;
            const float g3 = acc[3][r] - xe * cx[3] - he * ch[3] + bsum[3] + z;

            const float ig = sigmoidf_(g0);
            const float fg = sigmoidf_(g1);
            const float og = sigmoidf_(g2);
            const float ng = tanhr_(g3);

            const float cn  = fg * cv[r] + ig * ng;
            const float hnv = og * tanhr_(cn);

            oh_[buf][rl * 68 + jl] = hnv;
            oc_[buf][rl * 68 + jl] = cn;
        }

        if (mt < 7) {
#pragma unroll
            for (int ks = 0; ks < 4; ++ks) a[ks] = an[ks];
#pragma unroll
            for (int r = 0; r < 4; ++r) { xv[r] = xn[r]; hv[r] = hn[r]; cv[r] = cn2[r]; }
        }
    }

    __syncthreads();
    {   // final out tile (mt = 7, buffer 1)
        const int gr = b0 + 7 * 16 + srow;
        f32x4 vh = *(const f32x4*)&oh_[1][sidx];
        f32x4 vc = *(const f32x4*)&oc_[1][sidx];
        *(f32x4*)(out + (size_t)gr * H_ + j0b + scol) = vh;
        *(f32x4*)(out + (size_t)B_ * H_ + (size_t)gr * H_ + j0b + scol) = vc;
    }
}

// ---------------------------------------------------------------------------
extern "C" void kernel_launch(void* const* d_in, const int* in_sizes, int n_in,
                              void* d_out, int out_size, void* d_ws, size_t ws_size,
                              hipStream_t stream) {
    const float* x     = (const float*)d_in[0];
    const float* h     = (const float*)d_in[1];
    const float* c     = (const float*)d_in[2];
    const float* u_x   = (const float*)d_in[3];
    const float* u_h   = (const float*)d_in[4];
    const float* v_x   = (const float*)d_in[5];
    const float* v_h   = (const float*)d_in[6];
    const float* b_x   = (const float*)d_in[7];
    const float* b_h   = (const float*)d_in[8];
    const float* dia_x = (const float*)d_in[9];
    const float* dia_h = (const float*)d_in[10];
    float* out = (float*)d_out;

    char* ws = (char*)d_ws;
    short* P      = (short*)(ws);                                    // 2,097,152 B
    short* uxT    = (short*)(ws + 2097152);                          //    65,536
    short* uhT    = (short*)(ws + 2097152 + 65536);                  //   131,072
    short* Vc     = (short*)(ws + 2097152 + 65536 + 131072);         // 1,048,576
    float* coef_x = (float*)(ws + 2097152 + 65536 + 131072 + 1048576);
    float* coef_h = (float*)(ws + 2097152 + 65536 + 131072 + 1048576 + 8192);

    prep_kernel<<<2816, 256, 0, stream>>>(u_x, u_h, v_x, v_h, uxT, uhT, Vc, coef_x, coef_h);
    stage1_kernel<<<dim3(512, 2), 256, 0, stream>>>(x, h, uxT, uhT, P);
    stage2_kernel<<<dim3(64, 16), 256, 0, stream>>>(P, Vc, x, h, c,
                                                    coef_x, coef_h, b_x, b_h,
                                                    dia_x, dia_h, out);
}